// Round 1
// baseline (435.276 us; speedup 1.0000x reference)
//
#include <hip/hip_runtime.h>
#include <math.h>

#define NEGV -10000000000.0f

// One block per batch element. Thread j owns DP column (j+1).
// Anti-diagonal wavefront: at step t, thread j computes cell (i, c) =
// (t - j + 1, j + 1), valid when j <= t < j + N.
//   up   V[i-1][c]   = own value from step t-1          (register v_prev)
//   left V[i][c-1]   = thread j-1's value from step t-1 (shuffle / LDS boundary)
//   diag V[i-1][c-1] = thread j-1's value from step t-2 (= my v_left of step t-1)
__global__ __launch_bounds__(512, 1) void nw_kernel(
    const float* __restrict__ theta, const float* __restrict__ A,
    float* __restrict__ out, int N, int M)
{
    const int b    = blockIdx.x;
    const int j    = threadIdx.x;   // column j+1
    const int lane = j & 63;
    const int w    = j >> 6;        // wave index within block

    // Double-buffered cross-wave boundary: bnd[t&1][w] = wave w lane63 value at step t
    __shared__ float bnd[2][8];
    if (j < 16) bnd[j >> 3][j & 7] = NEGV;
    __syncthreads();

    const float a = A[b];
    const float* thp = theta + (size_t)b * N * M + j;  // column j of theta[b]

    float v_prev = NEGV;                       // V[0][j+1]
    float v_diag = (j == 0) ? 0.0f : NEGV;     // V[0][j]

    // theta for step t is thp[(t-j)*M]; clamp row for inactive steps (value unused).
    auto ldth = [&](int t) -> float {
        int r = t - j;
        r = r < 0 ? 0 : (r > N - 1 ? N - 1 : r);
        return thp[(size_t)r * M];
    };
    // Prefetch ring, depth 4 (covers L2/HBM first-touch latency).
    float th0 = ldth(0), th1 = ldth(1), th2 = ldth(2), th3 = ldth(3);

    const int T = N + M - 1;
    for (int t = 0; t < T; ++t) {
        float th_new = ldth(t + 4);

        float v_left = __shfl_up(v_prev, 1, 64);
        if (lane == 0)
            v_left = (w == 0) ? NEGV : bnd[(t + 1) & 1][w - 1];

        // logsumexp(a+up, diag, a+left)
        float x = a + v_prev;
        float y = v_diag;
        float z = a + v_left;
        float m = fmaxf(fmaxf(x, y), z);
        float s = __expf(x - m) + __expf(y - m) + __expf(z - m);
        float v_new = th0 + m + __logf(s);

        bool active = (t >= j) && (t < j + N);
        v_new = active ? v_new : NEGV;

        if (lane == 63) bnd[t & 1][w] = v_new;
        __syncthreads();   // publishes bnd[t&1]; guards reuse of bnd[(t+1)&1]

        v_diag = v_left;
        v_prev = v_new;
        th0 = th1; th1 = th2; th2 = th3; th3 = th_new;
    }

    // V[N][M] lives in thread M-1 after the last step.
    if (j == M - 1) out[b] = v_prev;
}

extern "C" void kernel_launch(void* const* d_in, const int* in_sizes, int n_in,
                              void* d_out, int out_size, void* d_ws, size_t ws_size,
                              hipStream_t stream) {
    const float* theta = (const float*)d_in[0];
    const float* A     = (const float*)d_in[1];
    float* out = (float*)d_out;

    const int B  = in_sizes[1];
    const int NM = in_sizes[0] / B;
    int N = 1;
    while (N * N < NM) N <<= 1;   // N*M square power-of-two (512x512 expected)
    const int M = NM / N;

    hipLaunchKernelGGL(nw_kernel, dim3(B), dim3(M), 0, stream,
                       theta, A, out, N, M);
}

// Round 2
// 272.836 us; speedup vs baseline: 1.5954x; 1.5954x over previous
//
#include <hip/hip_runtime.h>
#include <math.h>

#define NEGV -10000000000.0f

constexpr int CSTEP = 12;        // diagonal steps per superstep
constexpr int RROWS = 76;        // padded rows per wave parallelogram (need 75)
constexpr int WROW  = CSTEP + 1; // 13 words/row -> bank stride 13 (coprime 32)

// One block per batch. Thread j owns DP column j+1. Waves are time-skewed:
// wave w computes chunk c (= 12 diagonal steps) at superstep S = w + c.
// Cross-wave boundary (lane 63 -> next wave's lane 0) goes through a
// double-buffered LDS chunk written one superstep ahead of its consumer.
// Theta is staged coalesced (row-wise) into LDS one chunk ahead.
__global__ __launch_bounds__(512, 1) void nw_kernel(
    const float* __restrict__ theta, const float* __restrict__ A,
    float* __restrict__ out, int N, int M)
{
    __shared__ float th_lds[8][2][RROWS][WROW];   // 63,232 B
    __shared__ float bnd[9][2][CSTEP];            //    864 B

    const int b   = blockIdx.x;
    const int tid = threadIdx.x;
    const int w   = tid >> 6;
    const int l   = tid & 63;
    const int j   = tid;                 // owns column j+1

    // wave 0's boundary source is the DP left edge: always NEG. Written once.
    if (tid < 2 * CSTEP) ((float*)bnd[0])[tid] = NEGV;

    const float a = A[b];
    const float* thb = theta + (size_t)b * N * M;

    float v_prev = NEGV;                       // V[i][j+1] running value
    float v_diag = (j == 0) ? 0.0f : NEGV;     // V[0][0] = 0 seeds thread 0
    float bcarry = NEGV;                       // neighbor boundary, last step of prev chunk

    const int T  = N + M - 1;
    const int KC = (T + CSTEP - 1) / CSTEP;    // number of chunks per wave

    // staging lane constants: 16 lanes per row, 4 rows per iteration
    const int  qw    = l & 15;                 // word (and col) offset in row
    const int  rlane = l >> 4;                 // row sub-index 0..3
    const int  col0  = 64 * w + 63 - rlane + qw;
    const bool wmask = (qw < WROW);            // words 0..12 (12 = pad, never read)

    for (int S = -1; S <= KC + 6; ++S) {
        // ---------- stage next chunk's theta (global -> regs) ----------
        const int cn = S - w + 1;
        const bool do_stage = (cn >= 0) && (cn < KC);
        float stg[19];
        if (do_stage) {
            const int t0n = cn * CSTEP;
            const int rb  = t0n - 64 * w - 63;
            #pragma unroll
            for (int it = 0; it < 19; ++it) {
                int r   = rb + it * 4 + rlane;
                int col = col0 - it * 4;
                r   = min(max(r, 0), N - 1);      // clamped lanes feed unused words
                col = min(max(col, 0), M - 1);
                stg[it] = thb[(size_t)r * M + col];
            }
        }

        // ---------- compute current chunk ----------
        const int c = S - w;
        if (c >= 0 && c < KC) {
            const int p = c & 1;

            // neighbor-wave boundary values for this chunk (uniform broadcast reads)
            float bv[CSTEP];
            #pragma unroll
            for (int k = 0; k < CSTEP; ++k) bv[k] = bnd[w][p][k];

            // theta for this chunk: row s = k - l + 63, word k -> base + 14k words
            float th[CSTEP];
            {
                const float* base = &th_lds[w][p][63 - l][0];
                #pragma unroll
                for (int k = 0; k < CSTEP; ++k) th[k] = base[k * (WROW + 1)];
            }

            const int tmj = c * CSTEP - j;   // t - j at k = 0
            #pragma unroll
            for (int k = 0; k < CSTEP; ++k) {
                // left neighbor's post-(t-1) value: DPP wave shift-right by 1.
                // Invalid lane 0 receives `old` = boundary value from prev wave.
                float bk = (k == 0) ? bcarry : bv[k - 1];
                int vli = __builtin_amdgcn_update_dpp(
                    __float_as_int(bk), __float_as_int(v_prev),
                    0x138 /* wave_shr:1 */, 0xF, 0xF, false);
                float vl = __int_as_float(vli);

                float x = a + v_prev;        // up
                float z = a + vl;            // left
                float m = fmaxf(fmaxf(x, v_diag), z);
                float s = __expf(x - m) + __expf(v_diag - m) + __expf(z - m);
                float v = th[k] + m + __logf(s);

                int dt = tmj + k;            // = t - j = row-1 of this cell
                // pre-activation -> NEG; active -> v; post-deactivation -> freeze
                float vn = ((unsigned)dt < (unsigned)N) ? v
                                                        : (dt < 0 ? NEGV : v_prev);
                if (l == 63) bnd[w + 1][p][k] = vn;   // publish to next wave
                v_diag = vl;
                v_prev = vn;
            }
            bcarry = bv[CSTEP - 1];
        }

        // ---------- write staged theta (regs -> LDS, other parity) ----------
        if (do_stage && wmask) {
            const int pn = cn & 1;
            #pragma unroll
            for (int it = 0; it < 19; ++it) {
                th_lds[w][pn][it * 4 + rlane][qw] = stg[it];
            }
        }

        __syncthreads();   // publishes staged theta + boundary chunk
    }

    if (j == M - 1) out[b] = v_prev;   // V[N][M], frozen at t = j+N-1
}

extern "C" void kernel_launch(void* const* d_in, const int* in_sizes, int n_in,
                              void* d_out, int out_size, void* d_ws, size_t ws_size,
                              hipStream_t stream) {
    const float* theta = (const float*)d_in[0];
    const float* A     = (const float*)d_in[1];
    float* out = (float*)d_out;

    const int B  = in_sizes[1];
    const int NM = in_sizes[0] / B;
    int N = 1;
    while (N * N < NM) N <<= 1;   // 512x512 expected
    const int M = NM / N;

    hipLaunchKernelGGL(nw_kernel, dim3(B), dim3(M), 0, stream,
                       theta, A, out, N, M);
}

// Round 3
// 213.633 us; speedup vs baseline: 2.0375x; 1.2771x over previous
//
#include <hip/hip_runtime.h>
#include <math.h>

#define NEGV  -10000000000.0f
#define LOG2E 1.44269504088896340736f
#define LN2F  0.69314718055994530942f

typedef float f4 __attribute__((ext_vector_type(4)));

constexpr int CS   = 16;          // diagonal steps per chunk
constexpr int ROWS = 80;          // staged rows per wave-chunk (need 79)
constexpr int WL   = 17;          // LDS words per row (16 data + 1 pad; 17 coprime 32)
constexpr int CHW  = ROWS * WL;   // words per chunk buffer (1360)

// One block per batch. Thread j owns DP column j+1. Waves time-skewed by one
// 16-step chunk; cross-wave boundary via double-buffered LDS chunk. Theta
// staged coalesced (4 rows x 16 cols per load-iteration) one chunk ahead,
// pre-scaled by log2e; LSE computed in base-2 domain (saves the exp/log
// scaling muls). Waves skip chunks entirely outside their active window.
__global__ __launch_bounds__(512, 2) void nw_kernel(
    const float* __restrict__ theta, const float* __restrict__ A,
    float* __restrict__ out, int N, int M)
{
    __shared__ float thS[8 * 2 * CHW];    // 87,040 B
    __shared__ f4    bndS4[9 * 2 * 4];    // [wave 0..8][parity][16 floats]
    float* bndS = (float*)bndS4;

    const int tid = threadIdx.x;
    const int w   = tid >> 6;
    const int l   = tid & 63;
    const int j   = tid;
    const int b   = blockIdx.x;
    const int NW  = blockDim.x >> 6;

    if (tid < 9 * 2 * 16) bndS[tid] = NEGV;   // boundary slots default NEG

    const float a2 = A[b] * LOG2E;
    const float* __restrict__ thb = theta + (size_t)b * N * M;
    const int NM = N * M;

    float v_prev = NEGV;                    // V2[i][j+1] running value
    float v_diag = (j == 0) ? 0.0f : NEGV;  // V2[0][0] = 0 seeds thread 0
    float bcarry = NEGV;                    // neighbor boundary at last step of prev chunk

    const int T  = N + M - 1;
    const int KC = (T + CS - 1) / CS;

    // staging lane constants: 20 iterations x (4 rows x 16 cols)
    const int srow = l >> 4;                // 0..3
    const int sq   = l & 15;                // 0..15
    const int lanebase = srow * (M - 1) + 64 * w + 63 + sq;   // word offset vs rb*M
    const int wrbase0 = (w * 2 + 0) * CHW + srow * WL + sq;
    const int wrbase1 = (w * 2 + 1) * CHW + srow * WL + sq;
    const int rdbase0 = (w * 2 + 0) * CHW + (63 - l) * WL;
    const int rdbase1 = (w * 2 + 1) * CHW + (63 - l) * WL;

    const int wstart = 64 * w;              // first active step t of this wave
    const int wend   = 64 * w + 63 + N - 1; // last active step t

    for (int S = -1; S <= KC - 1 + (NW - 1); ++S) {
        // ---------- stage next chunk's theta (global -> regs) ----------
        const int cn = S - w + 1;
        const bool st_act = (cn >= 0) && (cn < KC) &&
                            (CS * cn + CS - 1 >= wstart) && (CS * cn <= wend);
        float stg[20];
        if (st_act) {
            const int rb = CS * cn - 64 * w - 63;
            if (rb >= 0 && rb + (ROWS - 1) <= N - 1) {
                // interior: uniform pointer stride (SALU) + fixed lane offset
                const float* p = thb + (size_t)rb * M;
                #pragma unroll
                for (int it = 0; it < 20; ++it) {
                    stg[it] = p[lanebase];
                    p += 4 * (M - 1);
                }
            } else {
                // edge: flat clamp (clamped values feed only masked cells)
                const int rbM = rb * M;
                #pragma unroll
                for (int it = 0; it < 20; ++it) {
                    int off = rbM + lanebase + it * 4 * (M - 1);
                    off = min(max(off, 0), NM - 1);
                    stg[it] = thb[off];
                }
            }
        }

        // ---------- compute current chunk ----------
        const int c = S - w;
        const bool valid_c = (c >= 0) && (c < KC);
        const int pc = c & 1;
        float nbcarry = bcarry;
        if (valid_c) nbcarry = bndS[(w * 2 + pc) * 16 + 15];  // race-free: producer
                                                              // writes other parity now
        const bool cp_act = valid_c &&
                            (CS * c + CS - 1 >= wstart) && (CS * c <= wend);
        if (cp_act) {
            const f4* bsrc = &bndS4[(w * 2 + pc) * 4];
            f4 bq0 = bsrc[0], bq1 = bsrc[1], bq2 = bsrc[2], bq3 = bsrc[3];
            float bv[16] = {bq0.x, bq0.y, bq0.z, bq0.w,  bq1.x, bq1.y, bq1.z, bq1.w,
                            bq2.x, bq2.y, bq2.z, bq2.w,  bq3.x, bq3.y, bq3.z, bq3.w};

            const int rdb = pc ? rdbase1 : rdbase0;
            float th[16];
            #pragma unroll
            for (int k = 0; k < 16; ++k) th[k] = thS[rdb + k * (WL + 1)];

            float res[16];
            const bool full = (CS * c >= 64 * w + 63) &&
                              (CS * c + CS - 1 <= 64 * w + N - 1);
            if (full) {
                #pragma unroll
                for (int k = 0; k < 16; ++k) {
                    float bk = (k == 0) ? bcarry : bv[k - 1];
                    float vl = __int_as_float(__builtin_amdgcn_update_dpp(
                        __float_as_int(bk), __float_as_int(v_prev),
                        0x138 /* wave_shr:1 */, 0xF, 0xF, false));
                    float x = a2 + v_prev;
                    float z = a2 + vl;
                    float m = fmaxf(fmaxf(x, v_diag), z);
                    float s = __builtin_amdgcn_exp2f(x - m)
                            + __builtin_amdgcn_exp2f(v_diag - m)
                            + __builtin_amdgcn_exp2f(z - m);
                    float v = th[k] + m + __builtin_amdgcn_logf(s);
                    res[k]  = v;
                    v_diag  = vl;
                    v_prev  = v;
                }
            } else {
                const int tmj = CS * c - j;
                #pragma unroll
                for (int k = 0; k < 16; ++k) {
                    float bk = (k == 0) ? bcarry : bv[k - 1];
                    float vl = __int_as_float(__builtin_amdgcn_update_dpp(
                        __float_as_int(bk), __float_as_int(v_prev),
                        0x138, 0xF, 0xF, false));
                    float x = a2 + v_prev;
                    float z = a2 + vl;
                    float m = fmaxf(fmaxf(x, v_diag), z);
                    float s = __builtin_amdgcn_exp2f(x - m)
                            + __builtin_amdgcn_exp2f(v_diag - m)
                            + __builtin_amdgcn_exp2f(z - m);
                    float v = th[k] + m + __builtin_amdgcn_logf(s);
                    int dt  = tmj + k;   // t - j; active cell iff 0 <= dt < N
                    float vn = ((unsigned)dt < (unsigned)N) ? v
                                                            : (dt < 0 ? NEGV : v_prev);
                    res[k]  = vn;
                    v_diag  = vl;
                    v_prev  = vn;
                }
            }
            if (l == 63) {
                f4* dst = &bndS4[((w + 1) * 2 + pc) * 4];
                dst[0] = (f4){res[0],  res[1],  res[2],  res[3]};
                dst[1] = (f4){res[4],  res[5],  res[6],  res[7]};
                dst[2] = (f4){res[8],  res[9],  res[10], res[11]};
                dst[3] = (f4){res[12], res[13], res[14], res[15]};
            }
        }
        bcarry = nbcarry;

        // ---------- write staged theta (regs -> LDS), pre-scaled ----------
        if (st_act) {
            const int wb = (cn & 1) ? wrbase1 : wrbase0;
            #pragma unroll
            for (int it = 0; it < 20; ++it)
                thS[wb + it * 4 * WL] = stg[it] * LOG2E;
        }
        __syncthreads();
    }

    if (j == M - 1) out[b] = v_prev * LN2F;   // back to natural-log domain
}

extern "C" void kernel_launch(void* const* d_in, const int* in_sizes, int n_in,
                              void* d_out, int out_size, void* d_ws, size_t ws_size,
                              hipStream_t stream) {
    const float* theta = (const float*)d_in[0];
    const float* A     = (const float*)d_in[1];
    float* out = (float*)d_out;

    const int B  = in_sizes[1];
    const int NM = in_sizes[0] / B;
    int N = 1;
    while (N * N < NM) N <<= 1;   // 512x512 expected
    const int M = NM / N;

    hipLaunchKernelGGL(nw_kernel, dim3(B), dim3(M), 0, stream,
                       theta, A, out, N, M);
}

// Round 4
// 182.153 us; speedup vs baseline: 2.3896x; 1.1728x over previous
//
#include <hip/hip_runtime.h>
#include <math.h>

#define NEGV  -10000000000.0f
#define LOG2E 1.44269504088896340736f
#define LN2F  0.69314718055994530942f

typedef float f4 __attribute__((ext_vector_type(4)));

constexpr int CS    = 16;          // diagonal steps per chunk
constexpr int ROWS  = 80;          // staged rows per wave-chunk (need 79)
constexpr int WL    = 17;          // LDS words per row (16 data + 1 pad)
constexpr int CHW   = ROWS * WL;   // words per chunk buffer (1360)
constexpr int KCMAX = 64;          // chunk count for N=M=512

// One block per batch. Thread j owns DP column j+1. Waves free-run (NO global
// barrier): wave w publishes its lane-63 chunk boundary into a full-history
// LDS buffer bndD[w+1][c][16] and release-stores a per-chunk flag; wave w+1
// acquire-spins only while its lane 0 is still active. Theta LDS is
// wave-private (double-buffered per wave), staged coalesced one chunk ahead.
__global__ __launch_bounds__(512, 2) void nw_kernel(
    const float* __restrict__ theta, const float* __restrict__ A,
    float* __restrict__ out, int N, int M)
{
    __shared__ float thS[8 * 2 * CHW];         // 87,040 B (wave-private halves)
    __shared__ float bndD[9 * KCMAX * 16];     // 36,864 B full boundary history
    __shared__ int   flg[9 * KCMAX];           //  2,304 B

    const int tid = threadIdx.x;
    const int w   = tid >> 6;
    const int l   = tid & 63;
    const int j   = tid;                 // owns column j+1
    const int b   = blockIdx.x;
    const int NW  = blockDim.x >> 6;

    // zero flags; the ONLY block-wide barrier in the kernel
    for (int i = tid; i < 9 * KCMAX; i += blockDim.x) flg[i] = 0;
    __syncthreads();

    const float a2 = A[b] * LOG2E;
    const float* __restrict__ thb = theta + (size_t)b * N * M;
    const int NM = N * M;

    const int T  = N + M - 1;
    const int KC = (T + CS - 1) / CS;
    const int wstart = 64 * w;
    const int wend   = 64 * w + 63 + N - 1;
    const int ca = wstart / CS;                     // first chunk this wave computes
    const int cb = min(KC - 1, wend / CS);          // last chunk

    // staging lane constants: 20 iterations x (4 rows x 16 cols)
    const int srow = l >> 4;
    const int sq   = l & 15;
    const int lanebase = srow * (M - 1) + 64 * w + 63 + sq;
    const int wrbase0 = (w * 2 + 0) * CHW + srow * WL + sq;
    const int wrbase1 = (w * 2 + 1) * CHW + srow * WL + sq;
    const int rdbase0 = (w * 2 + 0) * CHW + (63 - l) * WL;
    const int rdbase1 = (w * 2 + 1) * CHW + (63 - l) * WL;

    auto stage_load = [&](int cn, float* stg) {
        const int rb = CS * cn - 64 * w - 63;
        if (rb >= 0 && rb + (ROWS - 1) <= N - 1) {
            const float* p = thb + (size_t)rb * M;   // uniform base + lane offset
            #pragma unroll
            for (int it = 0; it < 20; ++it) { stg[it] = p[lanebase]; p += 4 * (M - 1); }
        } else {
            const int rbM = rb * M;                  // edge: flat clamp
            #pragma unroll
            for (int it = 0; it < 20; ++it) {
                int off = rbM + lanebase + it * 4 * (M - 1);
                off = min(max(off, 0), NM - 1);
                stg[it] = thb[off];
            }
        }
    };
    auto stage_write = [&](int cn, const float* stg) {
        const int wb = (cn & 1) ? wrbase1 : wrbase0;
        #pragma unroll
        for (int it = 0; it < 20; ++it) thS[wb + it * 4 * WL] = stg[it] * LOG2E;
    };
    auto wait_flag = [&](int idx) {
        if (__atomic_load_n(&flg[idx], __ATOMIC_ACQUIRE) == 0) {
            do { __builtin_amdgcn_s_sleep(1); }
            while (__atomic_load_n(&flg[idx], __ATOMIC_ACQUIRE) == 0);
        }
    };

    float v_prev = NEGV;                    // V2[i][j+1] running value
    float v_diag = (j == 0) ? 0.0f : NEGV;  // V2[0][0] = 0 seeds thread 0
    float bcarry = NEGV;                    // neighbor boundary, step CS*c - 1

    // prologue: stage chunk ca into LDS (self-consumed; intra-wave ordering)
    {
        float s0[20];
        stage_load(ca, s0);
        stage_write(ca, s0);
        __asm__ volatile("s_waitcnt lgkmcnt(0)" ::: "memory");
    }
    if (w > 0) {                            // bcarry for first chunk is real data
        wait_flag(w * KCMAX + (ca - 1));
        bcarry = bndD[(w * KCMAX + ca - 1) * 16 + 15];
    }

    float stg[20];
    bool have = (ca + 1 <= cb);
    if (have) stage_load(ca + 1, stg);

    for (int c = ca; c <= cb; ++c) {
        // theta for this chunk (issue early; latency overlaps spin)
        const int rdb = (c & 1) ? rdbase1 : rdbase0;
        float th[16];
        #pragma unroll
        for (int k = 0; k < 16; ++k) th[k] = thS[rdb + k * (WL + 1)];

        // neighbor boundary — only while this wave's lane 0 is still active
        const bool need_bv = (w > 0) && (CS * c <= 64 * w + N - 1);
        float bv[16];
        if (need_bv) {
            wait_flag(w * KCMAX + c);
            const f4* src = (const f4*)&bndD[(w * KCMAX + c) * 16];
            f4 q0 = src[0], q1 = src[1], q2 = src[2], q3 = src[3];
            bv[0]=q0.x; bv[1]=q0.y; bv[2]=q0.z; bv[3]=q0.w;
            bv[4]=q1.x; bv[5]=q1.y; bv[6]=q1.z; bv[7]=q1.w;
            bv[8]=q2.x; bv[9]=q2.y; bv[10]=q2.z; bv[11]=q2.w;
            bv[12]=q3.x; bv[13]=q3.y; bv[14]=q3.z; bv[15]=q3.w;
        } else {
            #pragma unroll
            for (int k = 0; k < 16; ++k) bv[k] = NEGV;
        }

        float res[16];
        const bool full = (CS * c >= 64 * w + 63) &&
                          (CS * c + CS - 1 <= 64 * w + N - 1);
        if (full) {
            #pragma unroll
            for (int k = 0; k < 16; ++k) {
                float bk = (k == 0) ? bcarry : bv[k - 1];
                float vl = __int_as_float(__builtin_amdgcn_update_dpp(
                    __float_as_int(bk), __float_as_int(v_prev),
                    0x138 /* wave_shr:1 */, 0xF, 0xF, false));
                float x = a2 + v_prev;
                float z = a2 + vl;
                float m = fmaxf(fmaxf(x, v_diag), z);
                float s = __builtin_amdgcn_exp2f(x - m)
                        + __builtin_amdgcn_exp2f(v_diag - m)
                        + __builtin_amdgcn_exp2f(z - m);
                float v = th[k] + m + __builtin_amdgcn_logf(s);
                res[k] = v;
                v_diag = vl;
                v_prev = v;
            }
        } else {
            const int tmj = CS * c - j;
            #pragma unroll
            for (int k = 0; k < 16; ++k) {
                float bk = (k == 0) ? bcarry : bv[k - 1];
                float vl = __int_as_float(__builtin_amdgcn_update_dpp(
                    __float_as_int(bk), __float_as_int(v_prev),
                    0x138, 0xF, 0xF, false));
                float x = a2 + v_prev;
                float z = a2 + vl;
                float m = fmaxf(fmaxf(x, v_diag), z);
                float s = __builtin_amdgcn_exp2f(x - m)
                        + __builtin_amdgcn_exp2f(v_diag - m)
                        + __builtin_amdgcn_exp2f(z - m);
                float v = th[k] + m + __builtin_amdgcn_logf(s);
                int dt = tmj + k;            // t - j; active iff 0 <= dt < N
                float vn = ((unsigned)dt < (unsigned)N) ? v
                                                        : (dt < 0 ? NEGV : v_prev);
                res[k] = vn;
                v_diag = vl;
                v_prev = vn;
            }
        }

        // publish boundary to next wave, then release the flag
        if (w < NW - 1 && l == 63) {
            f4* dst = (f4*)&bndD[((w + 1) * KCMAX + c) * 16];
            dst[0] = (f4){res[0],  res[1],  res[2],  res[3]};
            dst[1] = (f4){res[4],  res[5],  res[6],  res[7]};
            dst[2] = (f4){res[8],  res[9],  res[10], res[11]};
            dst[3] = (f4){res[12], res[13], res[14], res[15]};
            __atomic_store_n(&flg[(w + 1) * KCMAX + c], 1, __ATOMIC_RELEASE);
        }
        bcarry = bv[15];

        // write staged theta for c+1, issue loads for c+2
        if (have) stage_write(c + 1, stg);
        have = (c + 2 <= cb);
        if (have) stage_load(c + 2, stg);
        __asm__ volatile("s_waitcnt lgkmcnt(0)" ::: "memory");
    }

    if (j == M - 1) out[b] = v_prev * LN2F;   // V[N][M], back to ln domain
}

extern "C" void kernel_launch(void* const* d_in, const int* in_sizes, int n_in,
                              void* d_out, int out_size, void* d_ws, size_t ws_size,
                              hipStream_t stream) {
    const float* theta = (const float*)d_in[0];
    const float* A     = (const float*)d_in[1];
    float* out = (float*)d_out;

    const int B  = in_sizes[1];
    const int NM = in_sizes[0] / B;
    int N = 1;
    while (N * N < NM) N <<= 1;   // 512x512 expected
    const int M = NM / N;

    hipLaunchKernelGGL(nw_kernel, dim3(B), dim3(M), 0, stream,
                       theta, A, out, N, M);
}